// Round 5
// baseline (195.003 us; speedup 1.0000x reference)
//
#include <hip/hip_runtime.h>
#include <hip/hip_bf16.h>

// Problem constants (B=1)
#define S_LEN 2048
#define E_DIM 1024
#define NH    16
#define HD    64
#define SM_SCALE 0.5f

typedef short bf16x8_t __attribute__((ext_vector_type(8)));   // 8 bf16 = 4 VGPRs
typedef float f32x4_t  __attribute__((ext_vector_type(4)));
typedef __bf16 bf16x4_t __attribute__((ext_vector_type(4)));

static __device__ __forceinline__ unsigned short f2bf_bits(float f) {
    return __builtin_bit_cast(unsigned short, (__bf16)f);
}

// async global->LDS, 16B per lane, dest = wave-uniform base + lane*16
#define GLD16(gp, lp) __builtin_amdgcn_global_load_lds(                       \
    (const __attribute__((address_space(1))) void*)(gp),                      \
    (__attribute__((address_space(3))) void*)(lp), 16, 0, 0)

// -------------------------------------------- merged prep: W^T + x->bf16
__global__ void k_prep(const float* __restrict__ x,
                       const float* __restrict__ Wq, const float* __restrict__ Wk,
                       const float* __restrict__ Wv, const float* __restrict__ Wo,
                       __bf16* __restrict__ xb, __bf16* __restrict__ wt) {
    const int z = blockIdx.z;
    if (z < 4) {
        __shared__ float tile[32][33];
        const float* W = z == 0 ? Wq : z == 1 ? Wk : z == 2 ? Wv : Wo;
        __bf16* o = wt + (size_t)z * E_DIM * E_DIM;
        const int tx = threadIdx.x, ty = threadIdx.y;
        const int bx = blockIdx.x * 32, by = blockIdx.y * 32;
#pragma unroll
        for (int j = 0; j < 32; j += 8)
            tile[ty + j][tx] = W[(size_t)(by + ty + j) * E_DIM + bx + tx];
        __syncthreads();
#pragma unroll
        for (int j = 0; j < 32; j += 8)
            o[(size_t)(bx + ty + j) * E_DIM + by + tx] = (__bf16)tile[tx][ty + j];
    } else {
        const int bid = (z - 4) * 1024 + blockIdx.y * 32 + blockIdx.x;
        const int tid = threadIdx.y * 32 + threadIdx.x;
        const int i = bid * 256 + tid;
        const float4 v = ((const float4*)x)[i];
        bf16x4_t o4;
        o4.x = (__bf16)v.x; o4.y = (__bf16)v.y; o4.z = (__bf16)v.z; o4.w = (__bf16)v.w;
        ((bf16x4_t*)xb)[i] = o4;
    }
}

// ------------------------------------------------------- QKV projection GEMM
// 64x128 tile, BK=32. Epilogue scatters into MFMA-fragment-native layout:
//   Q/K: frag[h][tile s>>6][t=(s>>4)&3][c=d>>5][lane=(d>>3&3)*16+(s&15)][j=d&7]
//   V  : frag[h][tile s>>6][t=d>>4][c=(s>>5)&1][lane=(s>>3&3)*16+(d&15)][j=s&7]
// so k_attn reads every MFMA operand as one coalesced 1KB global b128 load.
__global__ __launch_bounds__(256) void k_gemm_qkv(
    const __bf16* __restrict__ xb, const __bf16* __restrict__ wt,
    const float* __restrict__ bq, const float* __restrict__ bk, const float* __restrict__ bv,
    __bf16* __restrict__ qkv) {
    __shared__ __align__(16) unsigned short As[64 * 32];
    __shared__ __align__(16) unsigned short Bs[128 * 32];

    const int z = blockIdx.z;
    const __bf16* Bt = wt + (size_t)z * E_DIM * E_DIM;      // W^T [n][k]
    const float* bias = z == 0 ? bq : z == 1 ? bk : bv;
    __bf16* out = qkv + (size_t)z * NH * S_LEN * HD;

    const int tid = threadIdx.x, w = tid >> 6, l = tid & 63;
    const int lm = l & 15, q4 = l >> 4;
    const int bm = blockIdx.y, bn = blockIdx.x;
    const int wm = w >> 1, wn = w & 1;

    const int sm = (w << 4) + (l >> 2);
    const int skk = (l & 3) << 3;
    const __bf16* Ag = xb + (size_t)(bm * 64 + sm) * E_DIM + skk;
    const __bf16* Bg = Bt + (size_t)(bn * 128 + sm) * E_DIM + skk;
    unsigned short* AsW = As + (w << 9);
    unsigned short* BsW = Bs + (w << 9);

    f32x4_t acc[2][4];
#pragma unroll
    for (int i = 0; i < 2; i++)
#pragma unroll
        for (int j = 0; j < 4; j++) { acc[i][j].x = 0.f; acc[i][j].y = 0.f; acc[i][j].z = 0.f; acc[i][j].w = 0.f; }

    for (int k0 = 0; k0 < E_DIM; k0 += 32) {
        __syncthreads();
        GLD16(Ag + k0, AsW);
        GLD16(Bg + k0, BsW);
        GLD16(Bg + (size_t)64 * E_DIM + k0, BsW + 2048);
        __syncthreads();

        bf16x8_t af[2], bfr[4];
#pragma unroll
        for (int mt = 0; mt < 2; mt++)
            af[mt] = *(const bf16x8_t*)&As[(wm * 32 + mt * 16 + lm) * 32 + q4 * 8];
#pragma unroll
        for (int nt = 0; nt < 4; nt++)
            bfr[nt] = *(const bf16x8_t*)&Bs[(wn * 64 + nt * 16 + lm) * 32 + q4 * 8];
#pragma unroll
        for (int mt = 0; mt < 2; mt++)
#pragma unroll
            for (int nt = 0; nt < 4; nt++)
                acc[mt][nt] = __builtin_amdgcn_mfma_f32_16x16x32_bf16(af[mt], bfr[nt], acc[mt][nt], 0, 0, 0);
    }

#pragma unroll
    for (int nt = 0; nt < 4; nt++) {
        const int n = bn * 128 + wn * 64 + nt * 16 + lm;
        const float bval = bias[n];
        const int h = n >> 6, d = n & 63;
        if (z == 2) {
            // V frag-native: tile=bm, t=d>>4, c=wm, lane=(q4p*16 + d&15), j = key&7
            const int t4 = d >> 4, flm = d & 15;
#pragma unroll
            for (int mt = 0; mt < 2; mt++) {
                const int q4p = (mt * 2 + (q4 >> 1)) & 3;
                const int j0 = (q4 & 1) * 4;
                __bf16* ob = out + ((((size_t)h * 32 + bm) * 4 + t4) * 2 + wm) * 512
                                 + (q4p * 16 + flm) * 8 + j0;
                union { unsigned short s[4]; uint2 u; } pk;
#pragma unroll
                for (int i = 0; i < 4; i++) pk.s[i] = f2bf_bits(acc[mt][nt][i] + bval);
                *(uint2*)ob = pk.u;
            }
        } else {
            // Q/K frag-native: tile=s>>6, t=(s>>4)&3, c=d>>5, lane=((d>>3&3)*16 + s&15), j=d&7
            const float scale = (z == 0) ? SM_SCALE : 1.0f;   // fold SM_SCALE into Q (exact: pow2)
            const int c = d >> 5, q4p = (d >> 3) & 3, j = d & 7;
#pragma unroll
            for (int mt = 0; mt < 2; mt++) {
                const int s0 = bm * 64 + wm * 32 + mt * 16;
                const int kt6 = s0 >> 6, t4 = (s0 >> 4) & 3;
                __bf16* ob = out + ((((size_t)h * 32 + kt6) * 4 + t4) * 2 + c) * 512
                                 + (q4p * 16 + q4 * 4) * 8 + j;
#pragma unroll
                for (int i = 0; i < 4; i++)
                    ob[i * 8] = (__bf16)((acc[mt][nt][i] + bval) * scale);
            }
        }
    }
}

// ------------------------------------------------------------- attention
// Frag-native K/V/Q: every MFMA operand is one coalesced 1KB global b128 load.
// No K/V LDS, ZERO barriers in the kt loop; waves fully independent.
// Block = 4 waves: rh=w>>1 (32 rows), parity p=w&1 over kt. No-max softmax
// (scores bounded); parity partials combine linearly at the end.
__global__ __launch_bounds__(256, 4) void k_attn(
    const __bf16* __restrict__ Qf, const __bf16* __restrict__ Kf, const __bf16* __restrict__ Vf,
    __bf16* __restrict__ attn) {
    __shared__ __align__(16) unsigned short Pl[4][32 * 72]; // per-wave P strip [row][key]
    __shared__ float Ll[2][64][8];                          // l-exchange

    // work-balanced swizzle: long q-tiles dispatched first
    const int b = blockIdx.x;
    int qt, h;
    if (b < 256) { qt = 16 + (b >> 4); h = b & 15; }
    else         { qt = 15 - ((b - 256) >> 4); h = (b - 256) & 15; }

    const int tid = threadIdx.x, w = tid >> 6, l = tid & 63;
    const int p = w & 1;       // kt parity
    const int rh = w >> 1;     // row half
    const int lm = l & 15, q4 = l >> 4;

    const __bf16* Qb = Qf + ((size_t)h * 32 + qt) * 4096;   // [rg4][c2][512]
    const __bf16* Kb = Kf + (size_t)h * 32 * 4096;          // per kt: [t4][c2][512]
    const __bf16* Vb = Vf + (size_t)h * 32 * 4096;

    const int qrow0 = qt * 64 + rh * 32;

    // Q A-frags pinned (pre-scaled by SM_SCALE): 2 row-groups x 2 k-chunks
    bf16x8_t qf[2][2];
#pragma unroll
    for (int rg = 0; rg < 2; rg++)
#pragma unroll
        for (int c = 0; c < 2; c++)
            qf[rg][c] = *(const bf16x8_t*)(Qb + (((rh * 2 + rg) * 2 + c) << 9) + l * 8);

    float lacc[2][4];
    f32x4_t oacc[2][4];
#pragma unroll
    for (int rg = 0; rg < 2; rg++)
#pragma unroll
        for (int i = 0; i < 4; i++) lacc[rg][i] = 0.f;
#pragma unroll
    for (int rg = 0; rg < 2; rg++)
#pragma unroll
        for (int t = 0; t < 4; t++) { oacc[rg][t].x = 0.f; oacc[rg][t].y = 0.f; oacc[rg][t].z = 0.f; oacc[rg][t].w = 0.f; }

    unsigned short* Pw = Pl[w];

    for (int kt = p; kt <= qt; kt += 2) {
        const __bf16* Kt = Kb + (size_t)kt * 4096;
        const __bf16* Vt = Vb + (size_t)kt * 4096;
        const bool diag = (kt == qt);
        // QK^T + exp + P-write per t: keeps sc transient (low VGPR peak)
#pragma unroll
        for (int t = 0; t < 4; t++) {
            bf16x8_t kf0 = *(const bf16x8_t*)(Kt + ((t * 2 + 0) << 9) + l * 8);
            bf16x8_t kf1 = *(const bf16x8_t*)(Kt + ((t * 2 + 1) << 9) + l * 8);
            f32x4_t s0, s1;
            s0.x = 0.f; s0.y = 0.f; s0.z = 0.f; s0.w = 0.f;
            s1 = s0;
            s0 = __builtin_amdgcn_mfma_f32_16x16x32_bf16(qf[0][0], kf0, s0, 0, 0, 0);
            s0 = __builtin_amdgcn_mfma_f32_16x16x32_bf16(qf[0][1], kf1, s0, 0, 0, 0);
            s1 = __builtin_amdgcn_mfma_f32_16x16x32_bf16(qf[1][0], kf0, s1, 0, 0, 0);
            s1 = __builtin_amdgcn_mfma_f32_16x16x32_bf16(qf[1][1], kf1, s1, 0, 0, 0);
            if (diag) {
                const int kcol = kt * 64 + t * 16 + lm;
#pragma unroll
                for (int i = 0; i < 4; i++) {
                    const int qr = qrow0 + q4 * 4 + i;
                    s0[i] = (kcol > qr) ? 0.f : __expf(s0[i]);
                    s1[i] = (kcol > qr + 16) ? 0.f : __expf(s1[i]);
                }
            } else {
#pragma unroll
                for (int i = 0; i < 4; i++) { s0[i] = __expf(s0[i]); s1[i] = __expf(s1[i]); }
            }
#pragma unroll
            for (int i = 0; i < 4; i++) {
                lacc[0][i] += s0[i];
                lacc[1][i] += s1[i];
                Pw[(q4 * 4 + i) * 72 + t * 16 + lm] = f2bf_bits(s0[i]);
                Pw[(16 + q4 * 4 + i) * 72 + t * 16 + lm] = f2bf_bits(s1[i]);
            }
        }
        // PV: pf from wave-private LDS, vf coalesced from global frag layout
#pragma unroll
        for (int c = 0; c < 2; c++) {
            bf16x8_t pf0 = *(const bf16x8_t*)&Pw[lm * 72 + c * 32 + q4 * 8];
            bf16x8_t pf1 = *(const bf16x8_t*)&Pw[(16 + lm) * 72 + c * 32 + q4 * 8];
#pragma unroll
            for (int t = 0; t < 4; t++) {
                bf16x8_t vf = *(const bf16x8_t*)(Vt + ((t * 2 + c) << 9) + l * 8);
                oacc[0][t] = __builtin_amdgcn_mfma_f32_16x16x32_bf16(pf0, vf, oacc[0][t], 0, 0, 0);
                oacc[1][t] = __builtin_amdgcn_mfma_f32_16x16x32_bf16(pf1, vf, oacc[1][t], 0, 0, 0);
            }
        }
    }

    // ---- parity combine (linear: no-max softmax) ----
    __syncthreads();                       // all PV reads done; Pl reusable
    float* Ex = (float*)Pl;                // 16KB O-exchange [rh*64+l][32] swizzled
    if (p == 1) {
#pragma unroll
        for (int rg = 0; rg < 2; rg++)
#pragma unroll
            for (int t = 0; t < 4; t++)
#pragma unroll
                for (int i = 0; i < 4; i++) {
                    const int idx = rg * 16 + t * 4 + i;
                    Ex[(rh * 64 + l) * 32 + ((idx + l) & 31)] = oacc[rg][t][i];
                }
#pragma unroll
        for (int rg = 0; rg < 2; rg++)
#pragma unroll
            for (int i = 0; i < 4; i++)
                Ll[rh][l][rg * 4 + i] = lacc[rg][i];
    }
    __syncthreads();
    if (p == 0) {
#pragma unroll
        for (int rg = 0; rg < 2; rg++)
#pragma unroll
            for (int t = 0; t < 4; t++)
#pragma unroll
                for (int i = 0; i < 4; i++) {
                    const int idx = rg * 16 + t * 4 + i;
                    oacc[rg][t][i] += Ex[(rh * 64 + l) * 32 + ((idx + l) & 31)];
                }
#pragma unroll
        for (int rg = 0; rg < 2; rg++)
#pragma unroll
            for (int i = 0; i < 4; i++)
                lacc[rg][i] += Ll[rh][l][rg * 4 + i];
#pragma unroll
        for (int off = 1; off <= 8; off <<= 1)
#pragma unroll
            for (int rg = 0; rg < 2; rg++)
#pragma unroll
                for (int i = 0; i < 4; i++)
                    lacc[rg][i] += __shfl_xor(lacc[rg][i], off, 64);
#pragma unroll
        for (int rg = 0; rg < 2; rg++)
#pragma unroll
            for (int i = 0; i < 4; i++) {
                const float rl = 1.f / lacc[rg][i];
                const int row = qrow0 + rg * 16 + q4 * 4 + i;
#pragma unroll
                for (int t = 0; t < 4; t++)
                    attn[(size_t)row * E_DIM + h * HD + t * 16 + lm] = (__bf16)(oacc[rg][t][i] * rl);
            }
    }
}

// --------------------------------------------------------- output projection
__global__ __launch_bounds__(256) void k_gemm_out(
    const __bf16* __restrict__ A, const __bf16* __restrict__ Bt,
    const float* __restrict__ bias, float* __restrict__ out) {
    __shared__ __align__(16) unsigned short As[64 * 32];
    __shared__ __align__(16) unsigned short Bs[128 * 32];

    const int tid = threadIdx.x, w = tid >> 6, l = tid & 63;
    const int lm = l & 15, q4 = l >> 4;
    const int bm = blockIdx.y, bn = blockIdx.x;
    const int wm = w >> 1, wn = w & 1;

    const int sm = (w << 4) + (l >> 2);
    const int skk = (l & 3) << 3;
    const __bf16* Ag = A + (size_t)(bm * 64 + sm) * E_DIM + skk;
    const __bf16* Bg = Bt + (size_t)(bn * 128 + sm) * E_DIM + skk;
    unsigned short* AsW = As + (w << 9);
    unsigned short* BsW = Bs + (w << 9);

    f32x4_t acc[2][4];
#pragma unroll
    for (int i = 0; i < 2; i++)
#pragma unroll
        for (int j = 0; j < 4; j++) { acc[i][j].x = 0.f; acc[i][j].y = 0.f; acc[i][j].z = 0.f; acc[i][j].w = 0.f; }

    for (int k0 = 0; k0 < E_DIM; k0 += 32) {
        __syncthreads();
        GLD16(Ag + k0, AsW);
        GLD16(Bg + k0, BsW);
        GLD16(Bg + (size_t)64 * E_DIM + k0, BsW + 2048);
        __syncthreads();

        bf16x8_t af[2], bfr[4];
#pragma unroll
        for (int mt = 0; mt < 2; mt++)
            af[mt] = *(const bf16x8_t*)&As[(wm * 32 + mt * 16 + lm) * 32 + q4 * 8];
#pragma unroll
        for (int nt = 0; nt < 4; nt++)
            bfr[nt] = *(const bf16x8_t*)&Bs[(wn * 64 + nt * 16 + lm) * 32 + q4 * 8];
#pragma unroll
        for (int mt = 0; mt < 2; mt++)
#pragma unroll
            for (int nt = 0; nt < 4; nt++)
                acc[mt][nt] = __builtin_amdgcn_mfma_f32_16x16x32_bf16(af[mt], bfr[nt], acc[mt][nt], 0, 0, 0);
    }

#pragma unroll
    for (int nt = 0; nt < 4; nt++) {
        const int n = bn * 128 + wn * 64 + nt * 16 + lm;
        const float bval = bias[n];
#pragma unroll
        for (int mt = 0; mt < 2; mt++) {
            const int r0 = bm * 64 + wm * 32 + mt * 16 + q4 * 4;
#pragma unroll
            for (int i = 0; i < 4; i++)
                out[(size_t)(r0 + i) * E_DIM + n] = acc[mt][nt][i] + bval;
        }
    }
}

extern "C" void kernel_launch(void* const* d_in, const int* in_sizes, int n_in,
                              void* d_out, int out_size, void* d_ws, size_t ws_size,
                              hipStream_t stream) {
    const float* x  = (const float*)d_in[0];
    const float* Wq = (const float*)d_in[1];
    const float* bq = (const float*)d_in[2];
    const float* Wk = (const float*)d_in[3];
    const float* bk = (const float*)d_in[4];
    const float* Wv = (const float*)d_in[5];
    const float* bv = (const float*)d_in[6];
    const float* Wo = (const float*)d_in[7];
    const float* bo = (const float*)d_in[8];
    float* out = (float*)d_out;

    char* ws = (char*)d_ws;
    __bf16* xb   = (__bf16*)(ws);                        // 4 MB  x bf16 [S][E]
    __bf16* wt   = (__bf16*)(ws + ((size_t)4  << 20));   // 4x2MB [Wq^T,Wk^T,Wv^T,Wo^T] bf16
    __bf16* qkv  = (__bf16*)(ws + ((size_t)12 << 20));   // frag-native Qf,Kf,Vf (4MB each)
    __bf16* attn = (__bf16*)(ws + ((size_t)24 << 20));   // 4 MB  [S][E] bf16

    k_prep<<<dim3(32, 32, 6), dim3(32, 8), 0, stream>>>(x, Wq, Wk, Wv, Wo, xb, wt);
    k_gemm_qkv<<<dim3(E_DIM / 128, S_LEN / 64, 3), 256, 0, stream>>>(xb, wt, bq, bk, bv, qkv);
    k_attn<<<dim3(512), 256, 0, stream>>>(
        qkv, qkv + (size_t)NH * S_LEN * HD, qkv + (size_t)2 * NH * S_LEN * HD, attn);
    k_gemm_out<<<dim3(E_DIM / 128, S_LEN / 64), 256, 0, stream>>>(
        attn, wt + (size_t)3 * E_DIM * E_DIM, bo, out);
}

// Round 6
// 155.799 us; speedup vs baseline: 1.2516x; 1.2516x over previous
//
#include <hip/hip_runtime.h>
#include <hip/hip_bf16.h>

// Problem constants (B=1)
#define S_LEN 2048
#define E_DIM 1024
#define NH    16
#define HD    64
#define SM_SCALE 0.5f

typedef short bf16x8_t __attribute__((ext_vector_type(8)));   // 8 bf16 = 4 VGPRs
typedef float f32x4_t  __attribute__((ext_vector_type(4)));
typedef __bf16 bf16x4_t __attribute__((ext_vector_type(4)));

static __device__ __forceinline__ unsigned short f2bf_bits(float f) {
    return __builtin_bit_cast(unsigned short, (__bf16)f);
}

// async global->LDS, 16B per lane, dest = wave-uniform base + lane*16
#define GLD16(gp, lp) __builtin_amdgcn_global_load_lds(                       \
    (const __attribute__((address_space(1))) void*)(gp),                      \
    (__attribute__((address_space(3))) void*)(lp), 16, 0, 0)

// -------------------------------------------- merged prep: W^T + x->bf16
__global__ void k_prep(const float* __restrict__ x,
                       const float* __restrict__ Wq, const float* __restrict__ Wk,
                       const float* __restrict__ Wv, const float* __restrict__ Wo,
                       __bf16* __restrict__ xb, __bf16* __restrict__ wt) {
    const int z = blockIdx.z;
    if (z < 4) {
        __shared__ float tile[32][33];
        const float* W = z == 0 ? Wq : z == 1 ? Wk : z == 2 ? Wv : Wo;
        __bf16* o = wt + (size_t)z * E_DIM * E_DIM;
        const int tx = threadIdx.x, ty = threadIdx.y;
        const int bx = blockIdx.x * 32, by = blockIdx.y * 32;
#pragma unroll
        for (int j = 0; j < 32; j += 8)
            tile[ty + j][tx] = W[(size_t)(by + ty + j) * E_DIM + bx + tx];
        __syncthreads();
#pragma unroll
        for (int j = 0; j < 32; j += 8)
            o[(size_t)(bx + ty + j) * E_DIM + by + tx] = (__bf16)tile[tx][ty + j];
    } else {
        const int bid = (z - 4) * 1024 + blockIdx.y * 32 + blockIdx.x;
        const int tid = threadIdx.y * 32 + threadIdx.x;
        const int i = bid * 256 + tid;
        const float4 v = ((const float4*)x)[i];
        bf16x4_t o4;
        o4.x = (__bf16)v.x; o4.y = (__bf16)v.y; o4.z = (__bf16)v.z; o4.w = (__bf16)v.w;
        ((bf16x4_t*)xb)[i] = o4;
    }
}

// ------------------------------------------------------- QKV projection GEMM
// 64x128 tile, BK=32. Epilogue scatters into MFMA-fragment-native layout
// (works for BOTH A- and B-operand reads — same lane->element function):
//   Q/K: frag[h][tile s>>6][t=(s>>4)&3][c=d>>5][lane=(d>>3&3)*16+(s&15)][j=d&7]
//   V  : frag[h][tile s>>6][t=d>>4][c=(s>>5)&1][lane=(s>>3&3)*16+(d&15)][j=s&7]
__global__ __launch_bounds__(256) void k_gemm_qkv(
    const __bf16* __restrict__ xb, const __bf16* __restrict__ wt,
    const float* __restrict__ bq, const float* __restrict__ bk, const float* __restrict__ bv,
    __bf16* __restrict__ qkv) {
    __shared__ __align__(16) unsigned short As[64 * 32];
    __shared__ __align__(16) unsigned short Bs[128 * 32];

    const int z = blockIdx.z;
    const __bf16* Bt = wt + (size_t)z * E_DIM * E_DIM;      // W^T [n][k]
    const float* bias = z == 0 ? bq : z == 1 ? bk : bv;
    __bf16* out = qkv + (size_t)z * NH * S_LEN * HD;

    const int tid = threadIdx.x, w = tid >> 6, l = tid & 63;
    const int lm = l & 15, q4 = l >> 4;
    const int bm = blockIdx.y, bn = blockIdx.x;
    const int wm = w >> 1, wn = w & 1;

    const int sm = (w << 4) + (l >> 2);
    const int skk = (l & 3) << 3;
    const __bf16* Ag = xb + (size_t)(bm * 64 + sm) * E_DIM + skk;
    const __bf16* Bg = Bt + (size_t)(bn * 128 + sm) * E_DIM + skk;
    unsigned short* AsW = As + (w << 9);
    unsigned short* BsW = Bs + (w << 9);

    f32x4_t acc[2][4];
#pragma unroll
    for (int i = 0; i < 2; i++)
#pragma unroll
        for (int j = 0; j < 4; j++) { acc[i][j].x = 0.f; acc[i][j].y = 0.f; acc[i][j].z = 0.f; acc[i][j].w = 0.f; }

    for (int k0 = 0; k0 < E_DIM; k0 += 32) {
        __syncthreads();
        GLD16(Ag + k0, AsW);
        GLD16(Bg + k0, BsW);
        GLD16(Bg + (size_t)64 * E_DIM + k0, BsW + 2048);
        __syncthreads();

        bf16x8_t af[2], bfr[4];
#pragma unroll
        for (int mt = 0; mt < 2; mt++)
            af[mt] = *(const bf16x8_t*)&As[(wm * 32 + mt * 16 + lm) * 32 + q4 * 8];
#pragma unroll
        for (int nt = 0; nt < 4; nt++)
            bfr[nt] = *(const bf16x8_t*)&Bs[(wn * 64 + nt * 16 + lm) * 32 + q4 * 8];
#pragma unroll
        for (int mt = 0; mt < 2; mt++)
#pragma unroll
            for (int nt = 0; nt < 4; nt++)
                acc[mt][nt] = __builtin_amdgcn_mfma_f32_16x16x32_bf16(af[mt], bfr[nt], acc[mt][nt], 0, 0, 0);
    }

#pragma unroll
    for (int nt = 0; nt < 4; nt++) {
        const int n = bn * 128 + wn * 64 + nt * 16 + lm;
        const float bval = bias[n];
        const int h = n >> 6, d = n & 63;
        if (z == 2) {
            // V frag-native: tile=bm, t=d>>4, c=wm, lane=(q4p*16 + d&15), j=key&7
            const int t4 = d >> 4, flm = d & 15;
#pragma unroll
            for (int mt = 0; mt < 2; mt++) {
                const int q4p = (mt * 2 + (q4 >> 1)) & 3;
                const int j0 = (q4 & 1) * 4;
                __bf16* ob = out + ((((size_t)h * 32 + bm) * 4 + t4) * 2 + wm) * 512
                                 + (q4p * 16 + flm) * 8 + j0;
                union { unsigned short s[4]; uint2 u; } pk;
#pragma unroll
                for (int i = 0; i < 4; i++) pk.s[i] = f2bf_bits(acc[mt][nt][i] + bval);
                *(uint2*)ob = pk.u;
            }
        } else {
            // Q/K frag-native: tile=s>>6, t=(s>>4)&3, c=d>>5, lane=((d>>3&3)*16 + s&15), j=d&7
            const float scale = (z == 0) ? SM_SCALE : 1.0f;   // fold SM_SCALE into Q (exact: pow2)
            const int c = d >> 5, q4p = (d >> 3) & 3, j = d & 7;
#pragma unroll
            for (int mt = 0; mt < 2; mt++) {
                const int s0 = bm * 64 + wm * 32 + mt * 16;
                const int kt6 = s0 >> 6, t4 = (s0 >> 4) & 3;
                __bf16* ob = out + ((((size_t)h * 32 + kt6) * 4 + t4) * 2 + c) * 512
                                 + (q4p * 16 + q4 * 4) * 8 + j;
#pragma unroll
                for (int i = 0; i < 4; i++)
                    ob[i * 8] = (__bf16)((acc[mt][nt][i] + bval) * scale);
            }
        }
    }
}

// ------------------------------------------------------------- attention
// 4 waves x 16 rows, all waves walk the full kt range (no parity, no combine).
// K+V tiles (frag-native, 8KB each) staged to LDS via GLD16, DOUBLE-BUFFERED:
// next tile's loads issue before current tile's compute, so the end-of-step
// barrier's vmcnt drain is ~free. Transposed-score form: S^T = K·Q^T
// (A=K frags, B=Q frags), O^T = V^T·P (A=V frags, B=P frags) -> P-writes are
// 4x ds_write_b64, epilogue packed 8B stores. No-max softmax (scores bounded).
__global__ __launch_bounds__(256, 2) void k_attn(
    const __bf16* __restrict__ Qf, const __bf16* __restrict__ Kf, const __bf16* __restrict__ Vf,
    __bf16* __restrict__ attn) {
    __shared__ __align__(16) unsigned short KVs[2][2][4096];  // [buf][K/V][8KB tile]
    __shared__ __align__(16) unsigned short Pl[4][16 * 72];   // per-wave P [row][key]

    // work-balanced swizzle: long q-tiles dispatched first
    const int b = blockIdx.x;
    int qt, h;
    if (b < 256) { qt = 16 + (b >> 4); h = b & 15; }
    else         { qt = 15 - ((b - 256) >> 4); h = (b - 256) & 15; }

    const int tid = threadIdx.x, w = tid >> 6, l = tid & 63;
    const int lm = l & 15, q4 = l >> 4;

    const __bf16* Qb = Qf + ((size_t)h * 32 + qt) * 4096;
    const __bf16* Kb = Kf + (size_t)h * 32 * 4096;
    const __bf16* Vb = Vf + (size_t)h * 32 * 4096;

    // Q B-frags pinned (pre-scaled by SM_SCALE): wave w = row tile t=w
    bf16x8_t qf[2];
#pragma unroll
    for (int c = 0; c < 2; c++)
        qf[c] = *(const bf16x8_t*)(Qb + ((w * 2 + c) << 9) + l * 8);

    float lacc = 0.f;
    f32x4_t oacc[4];   // O^T: per d-tile, lane holds (d=q4*4+i, row=lm)
#pragma unroll
    for (int t = 0; t < 4; t++) { oacc[t].x = 0.f; oacc[t].y = 0.f; oacc[t].z = 0.f; oacc[t].w = 0.f; }

    unsigned short* Pw = Pl[w];

    // prologue: stage tile 0 into buf 0 (wave w: chunks w and w+4 of K and V)
    {
        const __bf16* Kg = Kb;
        const __bf16* Vg = Vb;
        GLD16(Kg + (w << 9) + l * 8,      &KVs[0][0][(w << 9) + l * 8]);
        GLD16(Kg + ((w + 4) << 9) + l * 8, &KVs[0][0][((w + 4) << 9) + l * 8]);
        GLD16(Vg + (w << 9) + l * 8,      &KVs[0][1][(w << 9) + l * 8]);
        GLD16(Vg + ((w + 4) << 9) + l * 8, &KVs[0][1][((w + 4) << 9) + l * 8]);
    }
    __syncthreads();

    for (int s = 0; s <= qt; s++) {
        const int bb = s & 1;
        if (s < qt) {   // prefetch next tile into the other buffer
            const __bf16* Kg = Kb + (size_t)(s + 1) * 4096;
            const __bf16* Vg = Vb + (size_t)(s + 1) * 4096;
            GLD16(Kg + (w << 9) + l * 8,      &KVs[bb ^ 1][0][(w << 9) + l * 8]);
            GLD16(Kg + ((w + 4) << 9) + l * 8, &KVs[bb ^ 1][0][((w + 4) << 9) + l * 8]);
            GLD16(Vg + (w << 9) + l * 8,      &KVs[bb ^ 1][1][(w << 9) + l * 8]);
            GLD16(Vg + ((w + 4) << 9) + l * 8, &KVs[bb ^ 1][1][((w + 4) << 9) + l * 8]);
        }

        // S^T = K·Q^T : lane holds (key = t*16+q4*4+i, row = lm)
        f32x4_t st[4];
#pragma unroll
        for (int t = 0; t < 4; t++) { st[t].x = 0.f; st[t].y = 0.f; st[t].z = 0.f; st[t].w = 0.f; }
#pragma unroll
        for (int t = 0; t < 4; t++) {
            bf16x8_t kf0 = *(const bf16x8_t*)&KVs[bb][0][((t * 2 + 0) << 9) + l * 8];
            bf16x8_t kf1 = *(const bf16x8_t*)&KVs[bb][0][((t * 2 + 1) << 9) + l * 8];
            st[t] = __builtin_amdgcn_mfma_f32_16x16x32_bf16(kf0, qf[0], st[t], 0, 0, 0);
            st[t] = __builtin_amdgcn_mfma_f32_16x16x32_bf16(kf1, qf[1], st[t], 0, 0, 0);
        }
        // P = exp(S); causal mask only on diagonal tile (local coords suffice)
        if (s == qt) {
            const int rowl = w * 16 + lm;
#pragma unroll
            for (int t = 0; t < 4; t++)
#pragma unroll
                for (int i = 0; i < 4; i++) {
                    const int keyl = t * 16 + q4 * 4 + i;
                    st[t][i] = (keyl > rowl) ? 0.f : __expf(st[t][i]);
                }
        } else {
#pragma unroll
            for (int t = 0; t < 4; t++)
#pragma unroll
                for (int i = 0; i < 4; i++) st[t][i] = __expf(st[t][i]);
        }
#pragma unroll
        for (int t = 0; t < 4; t++)
            lacc += (st[t][0] + st[t][1]) + (st[t][2] + st[t][3]);
        // P-write: 4 consecutive keys per lane -> one b64 per t (wave-private)
#pragma unroll
        for (int t = 0; t < 4; t++) {
            union { unsigned short s4[4]; uint2 u; } pk;
#pragma unroll
            for (int i = 0; i < 4; i++) pk.s4[i] = f2bf_bits(st[t][i]);
            *(uint2*)&Pw[lm * 72 + t * 16 + q4 * 4] = pk.u;
        }
        // O^T += V^T·P : A = V frags (LDS), B = P frags (wave-private LDS)
#pragma unroll
        for (int c = 0; c < 2; c++) {
            bf16x8_t pf = *(const bf16x8_t*)&Pw[lm * 72 + c * 32 + q4 * 8];
#pragma unroll
            for (int t = 0; t < 4; t++) {
                bf16x8_t vf = *(const bf16x8_t*)&KVs[bb][1][((t * 2 + c) << 9) + l * 8];
                oacc[t] = __builtin_amdgcn_mfma_f32_16x16x32_bf16(vf, pf, oacc[t], 0, 0, 0);
            }
        }
        __syncthreads();   // all reads of buf bb done; prefetch of bb^1 landed
    }

    // l-reduction: row lm's partials live in lanes lm, lm+16, lm+32, lm+48
    lacc += __shfl_xor(lacc, 16, 64);
    lacc += __shfl_xor(lacc, 32, 64);
    const float rl = 1.f / lacc;
    const int row = qt * 64 + w * 16 + lm;
#pragma unroll
    for (int t = 0; t < 4; t++) {
        union { unsigned short s4[4]; uint2 u; } pk;
#pragma unroll
        for (int i = 0; i < 4; i++) pk.s4[i] = f2bf_bits(oacc[t][i] * rl);
        *(uint2*)(attn + (size_t)row * E_DIM + h * HD + t * 16 + q4 * 4) = pk.u;
    }
}

// --------------------------------------------------------- output projection
__global__ __launch_bounds__(256) void k_gemm_out(
    const __bf16* __restrict__ A, const __bf16* __restrict__ Bt,
    const float* __restrict__ bias, float* __restrict__ out) {
    __shared__ __align__(16) unsigned short As[64 * 32];
    __shared__ __align__(16) unsigned short Bs[128 * 32];

    const int tid = threadIdx.x, w = tid >> 6, l = tid & 63;
    const int lm = l & 15, q4 = l >> 4;
    const int bm = blockIdx.y, bn = blockIdx.x;
    const int wm = w >> 1, wn = w & 1;

    const int sm = (w << 4) + (l >> 2);
    const int skk = (l & 3) << 3;
    const __bf16* Ag = A + (size_t)(bm * 64 + sm) * E_DIM + skk;
    const __bf16* Bg = Bt + (size_t)(bn * 128 + sm) * E_DIM + skk;
    unsigned short* AsW = As + (w << 9);
    unsigned short* BsW = Bs + (w << 9);

    f32x4_t acc[2][4];
#pragma unroll
    for (int i = 0; i < 2; i++)
#pragma unroll
        for (int j = 0; j < 4; j++) { acc[i][j].x = 0.f; acc[i][j].y = 0.f; acc[i][j].z = 0.f; acc[i][j].w = 0.f; }

    for (int k0 = 0; k0 < E_DIM; k0 += 32) {
        __syncthreads();
        GLD16(Ag + k0, AsW);
        GLD16(Bg + k0, BsW);
        GLD16(Bg + (size_t)64 * E_DIM + k0, BsW + 2048);
        __syncthreads();

        bf16x8_t af[2], bfr[4];
#pragma unroll
        for (int mt = 0; mt < 2; mt++)
            af[mt] = *(const bf16x8_t*)&As[(wm * 32 + mt * 16 + lm) * 32 + q4 * 8];
#pragma unroll
        for (int nt = 0; nt < 4; nt++)
            bfr[nt] = *(const bf16x8_t*)&Bs[(wn * 64 + nt * 16 + lm) * 32 + q4 * 8];
#pragma unroll
        for (int mt = 0; mt < 2; mt++)
#pragma unroll
            for (int nt = 0; nt < 4; nt++)
                acc[mt][nt] = __builtin_amdgcn_mfma_f32_16x16x32_bf16(af[mt], bfr[nt], acc[mt][nt], 0, 0, 0);
    }

#pragma unroll
    for (int nt = 0; nt < 4; nt++) {
        const int n = bn * 128 + wn * 64 + nt * 16 + lm;
        const float bval = bias[n];
#pragma unroll
        for (int mt = 0; mt < 2; mt++) {
            const int r0 = bm * 64 + wm * 32 + mt * 16 + q4 * 4;
#pragma unroll
            for (int i = 0; i < 4; i++)
                out[(size_t)(r0 + i) * E_DIM + n] = acc[mt][nt][i] + bval;
        }
    }
}

extern "C" void kernel_launch(void* const* d_in, const int* in_sizes, int n_in,
                              void* d_out, int out_size, void* d_ws, size_t ws_size,
                              hipStream_t stream) {
    const float* x  = (const float*)d_in[0];
    const float* Wq = (const float*)d_in[1];
    const float* bq = (const float*)d_in[2];
    const float* Wk = (const float*)d_in[3];
    const float* bk = (const float*)d_in[4];
    const float* Wv = (const float*)d_in[5];
    const float* bv = (const float*)d_in[6];
    const float* Wo = (const float*)d_in[7];
    const float* bo = (const float*)d_in[8];
    float* out = (float*)d_out;

    char* ws = (char*)d_ws;
    __bf16* xb   = (__bf16*)(ws);                        // 4 MB  x bf16 [S][E]
    __bf16* wt   = (__bf16*)(ws + ((size_t)4  << 20));   // 4x2MB [Wq^T,Wk^T,Wv^T,Wo^T] bf16
    __bf16* qkv  = (__bf16*)(ws + ((size_t)12 << 20));   // frag-native Qf,Kf,Vf (4MB each)
    __bf16* attn = (__bf16*)(ws + ((size_t)24 << 20));   // 4 MB  [S][E] bf16

    k_prep<<<dim3(32, 32, 6), dim3(32, 8), 0, stream>>>(x, Wq, Wk, Wv, Wo, xb, wt);
    k_gemm_qkv<<<dim3(E_DIM / 128, S_LEN / 64, 3), 256, 0, stream>>>(xb, wt, bq, bk, bv, qkv);
    k_attn<<<dim3(512), 256, 0, stream>>>(
        qkv, qkv + (size_t)NH * S_LEN * HD, qkv + (size_t)2 * NH * S_LEN * HD, attn);
    k_gemm_out<<<dim3(E_DIM / 128, S_LEN / 64), 256, 0, stream>>>(
        attn, wt + (size_t)3 * E_DIM * E_DIM, bo, out);
}